// Round 4
// baseline (149.119 us; speedup 1.0000x reference)
//
#include <hip/hip_runtime.h>

// CoLL fused: y(p,c) = sum_{3x3} w[dq] * x(q,c) * co[bin(p,c), bin(q,c)]
// N=8, H=128, W=128, C=64, NUM_BINS=8

static constexpr int Nn = 8, Hh = 128, Ww = 128, Cc = 64;
static constexpr int TOT = Nn * Hh * Ww * Cc;        // 8388608 floats
static constexpr int TOT4 = TOT / 4;                 // 2097152 float4

// monotone float<->uint key (works for all finite floats incl. negatives)
__device__ __forceinline__ unsigned f2key(float f) {
    unsigned u = __float_as_uint(f);
    return (u & 0x80000000u) ? ~u : (u | 0x80000000u);
}
__device__ __forceinline__ float key2f(unsigned k) {
    unsigned u = (k & 0x80000000u) ? (k & 0x7FFFFFFFu) : ~k;
    return __uint_as_float(u);
}

__global__ void init_ws_k(unsigned* ws) {
    ws[0] = 0xFFFFFFFFu;  // running min key
    ws[1] = 0u;           // running max key
}

__global__ __launch_bounds__(256) void minmax_k(const float4* __restrict__ x4,
                                                unsigned* __restrict__ ws) {
    float lmin = 3.4028235e38f, lmax = -3.4028235e38f;
    for (int i = blockIdx.x * blockDim.x + threadIdx.x; i < TOT4;
         i += gridDim.x * blockDim.x) {
        float4 v = x4[i];
        lmin = fminf(lmin, fminf(fminf(v.x, v.y), fminf(v.z, v.w)));
        lmax = fmaxf(lmax, fmaxf(fmaxf(v.x, v.y), fmaxf(v.z, v.w)));
    }
#pragma unroll
    for (int off = 32; off; off >>= 1) {
        lmin = fminf(lmin, __shfl_xor(lmin, off, 64));
        lmax = fmaxf(lmax, __shfl_xor(lmax, off, 64));
    }
    __shared__ float smin[4], smax[4];
    int wid = threadIdx.x >> 6, lane = threadIdx.x & 63;
    if (lane == 0) { smin[wid] = lmin; smax[wid] = lmax; }
    __syncthreads();
    if (threadIdx.x == 0) {
        float bmin = smin[0], bmax = smax[0];
#pragma unroll
        for (int i = 1; i < 4; ++i) {
            bmin = fminf(bmin, smin[i]);
            bmax = fmaxf(bmax, smax[i]);
        }
        atomicMin(&ws[0], f2key(bmin));
        atomicMax(&ws[1], f2key(bmax));
    }
}

__device__ __forceinline__ int qbin(float v, float xmin, float scale) {
    float t = (v - xmin) * scale;      // >= 0 exactly (v >= xmin in f32)
    t = fminf(t, 7.0f);
    return (int)t;                     // trunc == floor for t >= 0
}

__global__ __launch_bounds__(256) void coll_k(const float* __restrict__ x,
                                              const float* __restrict__ co,
                                              const float* __restrict__ wsp,
                                              float* __restrict__ y,
                                              const unsigned* __restrict__ ws) {
    __shared__ float co_s[64];
    __shared__ float w_s[9];
    if (threadIdx.x < 64) co_s[threadIdx.x] = co[threadIdx.x];
    if (threadIdx.x < 9) w_s[threadIdx.x] = wsp[threadIdx.x];
    __syncthreads();

    const float xmin = key2f(ws[0]);
    const float xmax = key2f(ws[1]);
    const float scale = 8.0f / (xmax - xmin + 1e-8f);

    int i = blockIdx.x * 256 + threadIdx.x;   // float4 element index
    // layout: [N][H][W][C/4] of float4 ; 16 float4 per pixel
    int c4 = i & 15;
    int w = (i >> 4) & 127;
    int h = (i >> 11) & 127;
    int n = i >> 18;

    const float4* __restrict__ x4 = (const float4*)x;
    const int base = ((n * 128 + h) * 128 + w) * 16 + c4;

    float4 xc = x4[base];
    const int ipx = qbin(xc.x, xmin, scale) * 8;
    const int ipy = qbin(xc.y, xmin, scale) * 8;
    const int ipz = qbin(xc.z, xmin, scale) * 8;
    const int ipw = qbin(xc.w, xmin, scale) * 8;

    float ax = 0.f, ay = 0.f, az = 0.f, aw = 0.f;

#pragma unroll
    for (int dh = -1; dh <= 1; ++dh) {
        int hh = h + dh;
        if ((unsigned)hh >= 128u) continue;
#pragma unroll
        for (int dw = -1; dw <= 1; ++dw) {
            int ww2 = w + dw;
            if ((unsigned)ww2 >= 128u) continue;
            const float wt = w_s[(dh + 1) * 3 + (dw + 1)];
            float4 q = x4[((n * 128 + hh) * 128 + ww2) * 16 + c4];
            ax = fmaf(wt * q.x, co_s[ipx + qbin(q.x, xmin, scale)], ax);
            ay = fmaf(wt * q.y, co_s[ipy + qbin(q.y, xmin, scale)], ay);
            az = fmaf(wt * q.z, co_s[ipz + qbin(q.z, xmin, scale)], az);
            aw = fmaf(wt * q.w, co_s[ipw + qbin(q.w, xmin, scale)], aw);
        }
    }

    ((float4*)y)[base] = make_float4(ax, ay, az, aw);
}

extern "C" void kernel_launch(void* const* d_in, const int* in_sizes, int n_in,
                              void* d_out, int out_size, void* d_ws, size_t ws_size,
                              hipStream_t stream) {
    const float* x = (const float*)d_in[0];
    const float* co = (const float*)d_in[1];
    const float* wsp = (const float*)d_in[2];
    float* y = (float*)d_out;
    unsigned* ws = (unsigned*)d_ws;

    hipLaunchKernelGGL(init_ws_k, dim3(1), dim3(1), 0, stream, ws);
    hipLaunchKernelGGL(minmax_k, dim3(2048), dim3(256), 0, stream,
                       (const float4*)x, ws);
    hipLaunchKernelGGL(coll_k, dim3(TOT4 / 256), dim3(256), 0, stream,
                       x, co, wsp, y, ws);
}

// Round 5
// 147.923 us; speedup vs baseline: 1.0081x; 1.0081x over previous
//
#include <hip/hip_runtime.h>

// CoLL fused: y(p,c) = sum_{3x3} w[dq] * x(q,c) * co[bin(p,c), bin(q,c)]
// N=8, H=128, W=128, C=64, NUM_BINS=8

static constexpr int TOT = 8 * 128 * 128 * 64;   // 8388608 floats
static constexpr int TOT4 = TOT / 4;             // 2097152 float4
static constexpr int MM_THREADS = 2048 * 256;    // minmax grid; TOT4/MM_THREADS = 4

// monotone float<->uint key (all finite floats incl. negatives)
__device__ __forceinline__ unsigned f2key(float f) {
    unsigned u = __float_as_uint(f);
    return (u & 0x80000000u) ? ~u : (u | 0x80000000u);
}
__device__ __forceinline__ float key2f(unsigned k) {
    unsigned u = (k & 0x80000000u) ? (k & 0x7FFFFFFFu) : ~k;
    return __uint_as_float(u);
}

__global__ void init_ws_k(unsigned* ws) {
    ws[0] = 0xFFFFFFFFu;  // running min key
    ws[1] = 0u;           // running max key
}

__device__ __forceinline__ float min4(float4 v) {
    return fminf(fminf(v.x, v.y), fminf(v.z, v.w));
}
__device__ __forceinline__ float max4(float4 v) {
    return fmaxf(fmaxf(v.x, v.y), fmaxf(v.z, v.w));
}

// MLP=4: four independent compile-time-strided loads per thread, fully unrolled.
__global__ __launch_bounds__(256) void minmax_k(const float4* __restrict__ x4,
                                                unsigned* __restrict__ ws) {
    const int i = blockIdx.x * 256 + threadIdx.x;
    float4 a = x4[i];
    float4 b = x4[i + MM_THREADS];
    float4 c = x4[i + 2 * MM_THREADS];
    float4 d = x4[i + 3 * MM_THREADS];
    float lmin = fminf(fminf(min4(a), min4(b)), fminf(min4(c), min4(d)));
    float lmax = fmaxf(fmaxf(max4(a), max4(b)), fmaxf(max4(c), max4(d)));
#pragma unroll
    for (int off = 32; off; off >>= 1) {
        lmin = fminf(lmin, __shfl_xor(lmin, off, 64));
        lmax = fmaxf(lmax, __shfl_xor(lmax, off, 64));
    }
    __shared__ float smin[4], smax[4];
    const int wid = threadIdx.x >> 6, lane = threadIdx.x & 63;
    if (lane == 0) { smin[wid] = lmin; smax[wid] = lmax; }
    __syncthreads();
    if (threadIdx.x == 0) {
        float bmin = fminf(fminf(smin[0], smin[1]), fminf(smin[2], smin[3]));
        float bmax = fmaxf(fmaxf(smax[0], smax[1]), fmaxf(smax[2], smax[3]));
        atomicMin(&ws[0], f2key(bmin));
        atomicMax(&ws[1], f2key(bmax));
    }
}

__device__ __forceinline__ int qbin(float v, float xmin, float scale) {
    float t = (v - xmin) * scale;      // >= 0 exactly (v >= xmin in f32)
    t = fminf(t, 7.0f);
    return (int)t;                     // trunc == floor for t >= 0
}

__global__ __launch_bounds__(256) void coll_k(const float* __restrict__ x,
                                              const float* __restrict__ co,
                                              const float* __restrict__ wsp,
                                              float* __restrict__ y,
                                              const unsigned* __restrict__ ws) {
    __shared__ float co_s[64];
    __shared__ float w_s[9];
    __shared__ float cw[9 * 64];   // pre-multiplied w_spatial[tap] * co[row][col]
    if (threadIdx.x < 64) co_s[threadIdx.x] = co[threadIdx.x];
    if (threadIdx.x < 9) w_s[threadIdx.x] = wsp[threadIdx.x];
    __syncthreads();
#pragma unroll
    for (int idx = threadIdx.x; idx < 576; idx += 256)
        cw[idx] = w_s[idx >> 6] * co_s[idx & 63];
    __syncthreads();

    const float xmin = key2f(ws[0]);
    const float xmax = key2f(ws[1]);
    const float scale = 8.0f / (xmax - xmin + 1e-8f);

    const int i = blockIdx.x * 256 + threadIdx.x;  // float4 element index
    // layout: [N][H][W][C/4] of float4 ; 16 float4 per pixel
    const int c4 = i & 15;
    const int w = (i >> 4) & 127;
    const int h = (i >> 11) & 127;
    const int n = i >> 18;

    const float4* __restrict__ x4 = (const float4*)x;
    const int base = ((n * 128 + h) * 128 + w) * 16 + c4;

    const float4 xc = x4[base];
    const int ipx = qbin(xc.x, xmin, scale) * 8;
    const int ipy = qbin(xc.y, xmin, scale) * 8;
    const int ipz = qbin(xc.z, xmin, scale) * 8;
    const int ipw = qbin(xc.w, xmin, scale) * 8;

    float ax = 0.f, ay = 0.f, az = 0.f, aw = 0.f;

#pragma unroll
    for (int dh = -1; dh <= 1; ++dh) {
        const int hh = h + dh;
        if ((unsigned)hh >= 128u) continue;
#pragma unroll
        for (int dw = -1; dw <= 1; ++dw) {
            const int ww2 = w + dw;
            if ((unsigned)ww2 >= 128u) continue;
            const int t64 = ((dh + 1) * 3 + (dw + 1)) * 64;  // compile-time per unrolled tap
            const float4 q = x4[((n * 128 + hh) * 128 + ww2) * 16 + c4];
            ax = fmaf(q.x, cw[t64 + ipx + qbin(q.x, xmin, scale)], ax);
            ay = fmaf(q.y, cw[t64 + ipy + qbin(q.y, xmin, scale)], ay);
            az = fmaf(q.z, cw[t64 + ipz + qbin(q.z, xmin, scale)], az);
            aw = fmaf(q.w, cw[t64 + ipw + qbin(q.w, xmin, scale)], aw);
        }
    }

    ((float4*)y)[base] = make_float4(ax, ay, az, aw);
}

extern "C" void kernel_launch(void* const* d_in, const int* in_sizes, int n_in,
                              void* d_out, int out_size, void* d_ws, size_t ws_size,
                              hipStream_t stream) {
    const float* x = (const float*)d_in[0];
    const float* co = (const float*)d_in[1];
    const float* wsp = (const float*)d_in[2];
    float* y = (float*)d_out;
    unsigned* ws = (unsigned*)d_ws;

    hipLaunchKernelGGL(init_ws_k, dim3(1), dim3(1), 0, stream, ws);
    hipLaunchKernelGGL(minmax_k, dim3(2048), dim3(256), 0, stream,
                       (const float4*)x, ws);
    hipLaunchKernelGGL(coll_k, dim3(TOT4 / 256), dim3(256), 0, stream,
                       x, co, wsp, y, ws);
}

// Round 7
// 109.892 us; speedup vs baseline: 1.3570x; 1.3461x over previous
//
#include <hip/hip_runtime.h>

// CoLL fused, 2 dispatches, NO atomics:
//  A) reduce_k : per-block min/max partials -> d_ws (1024 float2)
//  B) coll_k   : redundant partial-reduce prologue, then fused 3x3 stencil
//     y(p,c) = sum_{3x3} w[dq] * x(q,c) * co[bin(p,c), bin(q,c)]
// N=8, H=128, W=128, C=64, NUM_BINS=8.  One image = 128*128*16 = 262144 float4.

static constexpr int IMG4 = 128 * 128 * 16;
static constexpr int NBLK = 1024, NTHR = 256;   // NBLK*NTHR == IMG4

__device__ __forceinline__ int qbin(float v, float xmin, float scale) {
    float t = (v - xmin) * scale;   // >= 0 exactly (v >= xmin in f32)
    t = fminf(t, 7.0f);
    return (int)t;                  // trunc == floor for t >= 0
}

__global__ __launch_bounds__(256) void reduce_k(const float4* __restrict__ x4,
                                                float2* __restrict__ part) {
    const int ofs = blockIdx.x * 256 + threadIdx.x;  // within-image float4 idx
    float4 v[8];
#pragma unroll
    for (int k = 0; k < 8; ++k) v[k] = x4[k * IMG4 + ofs];

    float lmin = v[0].x, lmax = v[0].x;
#pragma unroll
    for (int k = 0; k < 8; ++k) {
        lmin = fminf(lmin, fminf(fminf(v[k].x, v[k].y), fminf(v[k].z, v[k].w)));
        lmax = fmaxf(lmax, fmaxf(fmaxf(v[k].x, v[k].y), fmaxf(v[k].z, v[k].w)));
    }
#pragma unroll
    for (int off = 32; off; off >>= 1) {
        lmin = fminf(lmin, __shfl_xor(lmin, off, 64));
        lmax = fmaxf(lmax, __shfl_xor(lmax, off, 64));
    }
    __shared__ float smin[4], smax[4];
    const int wid = threadIdx.x >> 6, lane = threadIdx.x & 63;
    if (lane == 0) { smin[wid] = lmin; smax[wid] = lmax; }
    __syncthreads();
    if (threadIdx.x == 0) {
        part[blockIdx.x] = make_float2(
            fminf(fminf(smin[0], smin[1]), fminf(smin[2], smin[3])),
            fmaxf(fmaxf(smax[0], smax[1]), fmaxf(smax[2], smax[3])));
    }
}

__global__ __launch_bounds__(256) void coll_k(const float4* __restrict__ x4,
                                              const float* __restrict__ co,
                                              const float* __restrict__ wsp,
                                              float4* __restrict__ y4,
                                              const float2* __restrict__ part) {
    __shared__ float co_s[64], w_s[9];
    __shared__ float cw[9 * 64];   // pre-multiplied w_spatial[tap] * co[row][col]
    __shared__ float sred[8];      // [0..3] wave mins, [4..7] wave maxs

    if (threadIdx.x < 64) co_s[threadIdx.x] = co[threadIdx.x];
    if (threadIdx.x < 9)  w_s[threadIdx.x] = wsp[threadIdx.x];

    // prologue: every block redundantly reduces the 1024 partials (8 KB, L2-hot)
    float gmin = 3.4028235e38f, gmax = -3.4028235e38f;
#pragma unroll
    for (int j = 0; j < 4; ++j) {
        float2 p = part[threadIdx.x * 4 + j];
        gmin = fminf(gmin, p.x);
        gmax = fmaxf(gmax, p.y);
    }
#pragma unroll
    for (int off = 32; off; off >>= 1) {
        gmin = fminf(gmin, __shfl_xor(gmin, off, 64));
        gmax = fmaxf(gmax, __shfl_xor(gmax, off, 64));
    }
    const int wid = threadIdx.x >> 6, lane = threadIdx.x & 63;
    if (lane == 0) { sred[wid] = gmin; sred[4 + wid] = gmax; }
    __syncthreads();   // co_s, w_s, sred all visible

    for (int idx = threadIdx.x; idx < 576; idx += 256)
        cw[idx] = w_s[idx >> 6] * co_s[idx & 63];

    const float xmin = fminf(fminf(sred[0], sred[1]), fminf(sred[2], sred[3]));
    const float xmax = fmaxf(fmaxf(sred[4], sred[5]), fmaxf(sred[6], sred[7]));
    const float scale = 8.0f / ((xmax - xmin) + 1e-8f);
    __syncthreads();   // cw ready

    const int ofs = blockIdx.x * 256 + threadIdx.x;  // within-image float4 idx
    const int w = (ofs >> 4) & 127;
    const int h = (ofs >> 11) & 127;
    const bool wm = (w > 0), wp = (w < 127), hm = (h > 0), hp = (h < 127);

#pragma unroll 2
    for (int k = 0; k < 8; ++k) {
        const int base = k * IMG4 + ofs;
        const float4 xc = x4[base];
        const int bx = qbin(xc.x, xmin, scale), ipx = bx * 8;
        const int by = qbin(xc.y, xmin, scale), ipy = by * 8;
        const int bz = qbin(xc.z, xmin, scale), ipz = bz * 8;
        const int bw = qbin(xc.w, xmin, scale), ipw = bw * 8;

        // center tap (t=4): col bin == row bin
        float ax = xc.x * cw[4 * 64 + ipx + bx];
        float ay = xc.y * cw[4 * 64 + ipy + by];
        float az = xc.z * cw[4 * 64 + ipz + bz];
        float aw = xc.w * cw[4 * 64 + ipw + bw];

#define TAP(T, OFF) { \
        const float4 q = x4[base + (OFF)]; \
        ax = fmaf(q.x, cw[(T) * 64 + ipx + qbin(q.x, xmin, scale)], ax); \
        ay = fmaf(q.y, cw[(T) * 64 + ipy + qbin(q.y, xmin, scale)], ay); \
        az = fmaf(q.z, cw[(T) * 64 + ipz + qbin(q.z, xmin, scale)], az); \
        aw = fmaf(q.w, cw[(T) * 64 + ipw + qbin(q.w, xmin, scale)], aw); }

        if (hm && wm) TAP(0, -2064)
        if (hm)       TAP(1, -2048)
        if (hm && wp) TAP(2, -2032)
        if (wm)       TAP(3, -16)
        if (wp)       TAP(5,  16)
        if (hp && wm) TAP(6,  2032)
        if (hp)       TAP(7,  2048)
        if (hp && wp) TAP(8,  2064)
#undef TAP

        y4[base] = make_float4(ax, ay, az, aw);
    }
}

extern "C" void kernel_launch(void* const* d_in, const int* in_sizes, int n_in,
                              void* d_out, int out_size, void* d_ws, size_t ws_size,
                              hipStream_t stream) {
    const float4* x4 = (const float4*)d_in[0];
    const float*  co = (const float*)d_in[1];
    const float*  wsp = (const float*)d_in[2];
    float4* y4 = (float4*)d_out;
    float2* part = (float2*)d_ws;    // 1024 float2 = 8 KB scratch

    hipLaunchKernelGGL(reduce_k, dim3(NBLK), dim3(NTHR), 0, stream, x4, part);
    hipLaunchKernelGGL(coll_k, dim3(NBLK), dim3(NTHR), 0, stream,
                       x4, co, wsp, y4, part);
}